// Round 1
// baseline (140.053 us; speedup 1.0000x reference)
//
#include <hip/hip_runtime.h>
#include <math.h>

#define N_GRAPHS 4096
#define LATENT 32

__device__ __forceinline__ float fast_tanh(float x) {
    // tanh(x) = (e^{2x}-1)/(e^{2x}+1); clamp so exp can't overflow
    x = fminf(fmaxf(x, -15.f), 15.f);
    float e = __expf(2.f * x);
    return (e - 1.f) / (e + 1.f);
}

// Fused: per-node attention score + exp + segmented (sorted-batch) weighted sums.
// se[g]  += sum_i e_i          (i in graph g)
// sez[g] += sum_i e_i * z_i    (32-vector)
__global__ __launch_bounds__(256) void attn_seg_kernel(
    const float* __restrict__ z, const int* __restrict__ batch,
    const float* __restrict__ w1, const float* __restrict__ b1,
    const float* __restrict__ w2, const float* __restrict__ b2,
    float* __restrict__ se, float* __restrict__ sez, int n)
{
    int i = blockIdx.x * blockDim.x + threadIdx.x;
    int lane = threadIdx.x & 63;
    int iL = (i < n) ? i : (n - 1);       // clamp: extra lanes contribute e=0
    int g = batch[iL];

    // load this node's 32 latent values (wave reads contiguous 8KB)
    float zr[32];
    const float4* zp = reinterpret_cast<const float4*>(z + (size_t)iL * LATENT);
    #pragma unroll
    for (int q = 0; q < 8; ++q) {
        float4 v = zp[q];
        zr[4*q+0] = v.x; zr[4*q+1] = v.y; zr[4*q+2] = v.z; zr[4*q+3] = v.w;
    }

    // alpha_raw = tanh(z @ W1 + b1) @ w2 + b2   (weights uniform -> SGPR loads)
    float alpha = b2[0];
    #pragma unroll 4
    for (int j = 0; j < LATENT; ++j) {
        float acc = b1[j];
        #pragma unroll
        for (int k = 0; k < LATENT; ++k)
            acc = fmaf(zr[k], w1[k*LATENT + j], acc);
        alpha = fmaf(fast_tanh(acc), w2[j], alpha);
    }
    // global-max subtraction cancels in the per-graph normalization; skip it.
    float e = (i < n) ? __expf(alpha) : 0.f;

    // values to segment-sum: v[0]=e, v[1..32]=e*z[k]
    float v[33];
    v[0] = e;
    #pragma unroll
    for (int k = 0; k < LATENT; ++k) v[k+1] = e * zr[k];

    // wave-level segmented inclusive scan (batch is sorted -> contiguous runs)
    #pragma unroll
    for (int s = 1; s < 64; s <<= 1) {
        int gprev = __shfl_up(g, s);
        bool doadd = (lane >= s) && (gprev == g);
        #pragma unroll
        for (int t = 0; t < 33; ++t) {
            float vv = __shfl_up(v[t], s);
            if (doadd) v[t] += vv;
        }
    }
    // segment tails flush to global accumulators
    int gnext = __shfl_down(g, 1);
    bool tail = (lane == 63) || (gnext != g);
    if (tail) {
        atomicAdd(&se[g], v[0]);
        #pragma unroll
        for (int k = 0; k < LATENT; ++k)
            atomicAdd(&sez[g*LATENT + k], v[k+1]);
    }
}

// One wave per graph: graph_z = sez/(se+1e-8); 32->128->64->1 MLP with sigmoid.
__global__ __launch_bounds__(64) void mlp_kernel(
    const float* __restrict__ se, const float* __restrict__ sez,
    const float* __restrict__ m1w, const float* __restrict__ m1b,
    const float* __restrict__ m2w, const float* __restrict__ m2b,
    const float* __restrict__ m3w, const float* __restrict__ m3b,
    float* __restrict__ out)
{
    int gidx = blockIdx.x;
    int lane = threadIdx.x;
    float inv = 1.f / (se[gidx] + 1e-8f);
    float gz = (lane < LATENT) ? sez[gidx*LATENT + lane] * inv : 0.f;

    // layer 1: 32 -> 128 ; lane holds hidden[lane] (a0) and hidden[lane+64] (a1)
    float a0 = m1b[lane], a1 = m1b[lane + 64];
    #pragma unroll
    for (int k = 0; k < LATENT; ++k) {
        float zk = __shfl(gz, k);
        a0 = fmaf(zk, m1w[k*128 + lane], a0);
        a1 = fmaf(zk, m1w[k*128 + lane + 64], a1);
    }
    a0 = fmaxf(a0, 0.f); a1 = fmaxf(a1, 0.f);

    // layer 2: 128 -> 64 ; lane holds out2[lane]
    float b = m2b[lane];
    #pragma unroll
    for (int k = 0; k < 64; ++k) {
        float xk = __shfl(a0, k);
        b = fmaf(xk, m2w[k*64 + lane], b);
    }
    #pragma unroll
    for (int k = 0; k < 64; ++k) {
        float xk = __shfl(a1, k);
        b = fmaf(xk, m2w[(k+64)*64 + lane], b);
    }
    b = fmaxf(b, 0.f);

    // layer 3: 64 -> 1 ; butterfly reduce, sigmoid
    float p = b * m3w[lane];
    #pragma unroll
    for (int s = 32; s >= 1; s >>= 1)
        p += __shfl_xor(p, s);
    if (lane == 0)
        out[gidx] = 1.f / (1.f + __expf(-(p + m3b[0])));
}

extern "C" void kernel_launch(void* const* d_in, const int* in_sizes, int n_in,
                              void* d_out, int out_size, void* d_ws, size_t ws_size,
                              hipStream_t stream)
{
    const float* z    = (const float*)d_in[0];
    const int*   batch= (const int*)d_in[1];
    const float* aw1  = (const float*)d_in[2];
    const float* ab1  = (const float*)d_in[3];
    const float* aw2  = (const float*)d_in[4];
    const float* ab2  = (const float*)d_in[5];
    const float* m1w  = (const float*)d_in[6];
    const float* m1b  = (const float*)d_in[7];
    const float* m2w  = (const float*)d_in[8];
    const float* m2b  = (const float*)d_in[9];
    const float* m3w  = (const float*)d_in[10];
    const float* m3b  = (const float*)d_in[11];
    float* out = (float*)d_out;

    int n = in_sizes[0] / LATENT;   // 2,000,000 nodes

    float* se  = (float*)d_ws;          // [4096]
    float* sez = se + N_GRAPHS;         // [4096][32]
    hipMemsetAsync(d_ws, 0, (size_t)(N_GRAPHS * 33) * sizeof(float), stream);

    int blocks = (n + 255) / 256;
    attn_seg_kernel<<<blocks, 256, 0, stream>>>(z, batch, aw1, ab1, aw2, ab2, se, sez, n);
    mlp_kernel<<<N_GRAPHS, 64, 0, stream>>>(se, sez, m1w, m1b, m2w, m2b, m3w, m3b, out);
}

// Round 2
// 137.455 us; speedup vs baseline: 1.0189x; 1.0189x over previous
//
#include <hip/hip_runtime.h>
#include <math.h>

#define N_GRAPHS 4096
#define LATENT 32

__device__ __forceinline__ float fast_tanh(float x) {
    // tanh(x) = (e^{2x}-1)/(e^{2x}+1); clamp so exp can't overflow
    x = fminf(fmaxf(x, -15.f), 15.f);
    float e = __expf(2.f * x);
    return (e - 1.f) / (e + 1.f);
}

// Zero the 33*N_GRAPHS-float accumulator workspace (rocclr fillBuffer was 150us!)
__global__ __launch_bounds__(256) void zero_ws_kernel(float4* __restrict__ ws) {
    ws[blockIdx.x * 256 + threadIdx.x] = float4{0.f, 0.f, 0.f, 0.f};
}

// Fused: per-node attention score + exp + segmented (sorted-batch) weighted sums.
// se[g]  += sum_i e_i          (i in graph g)
// sez[g] += sum_i e_i * z_i    (32-vector)
__global__ __launch_bounds__(256) void attn_seg_kernel(
    const float* __restrict__ z, const int* __restrict__ batch,
    const float* __restrict__ w1, const float* __restrict__ b1,
    const float* __restrict__ w2, const float* __restrict__ b2,
    float* __restrict__ se, float* __restrict__ sez, int n)
{
    int i = blockIdx.x * blockDim.x + threadIdx.x;
    int lane = threadIdx.x & 63;
    int iL = (i < n) ? i : (n - 1);       // clamp: extra lanes contribute e=0
    int g = batch[iL];

    // load this node's 32 latent values (wave reads contiguous 8KB)
    float zr[32];
    const float4* zp = reinterpret_cast<const float4*>(z + (size_t)iL * LATENT);
    #pragma unroll
    for (int q = 0; q < 8; ++q) {
        float4 v = zp[q];
        zr[4*q+0] = v.x; zr[4*q+1] = v.y; zr[4*q+2] = v.z; zr[4*q+3] = v.w;
    }

    // alpha_raw = tanh(z @ W1 + b1) @ w2 + b2   (weights uniform -> SGPR loads)
    float alpha = b2[0];
    #pragma unroll 4
    for (int j = 0; j < LATENT; ++j) {
        float acc = b1[j];
        #pragma unroll
        for (int k = 0; k < LATENT; ++k)
            acc = fmaf(zr[k], w1[k*LATENT + j], acc);
        alpha = fmaf(fast_tanh(acc), w2[j], alpha);
    }
    // global-max subtraction cancels in the per-graph normalization; skip it.
    float e = (i < n) ? __expf(alpha) : 0.f;

    // values to segment-sum: v[0]=e, v[1..32]=e*z[k]
    float v[33];
    v[0] = e;
    #pragma unroll
    for (int k = 0; k < LATENT; ++k) v[k+1] = e * zr[k];

    // wave-level segmented inclusive scan (batch is sorted -> contiguous runs)
    #pragma unroll
    for (int s = 1; s < 64; s <<= 1) {
        int gprev = __shfl_up(g, s);
        bool doadd = (lane >= s) && (gprev == g);
        #pragma unroll
        for (int t = 0; t < 33; ++t) {
            float vv = __shfl_up(v[t], s);
            if (doadd) v[t] += vv;
        }
    }
    // segment tails flush to global accumulators
    int gnext = __shfl_down(g, 1);
    bool tail = (lane == 63) || (gnext != g);
    if (tail) {
        atomicAdd(&se[g], v[0]);
        #pragma unroll
        for (int k = 0; k < LATENT; ++k)
            atomicAdd(&sez[g*LATENT + k], v[k+1]);
    }
}

// One wave per graph: graph_z = sez/(se+1e-8); 32->128->64->1 MLP with sigmoid.
__global__ __launch_bounds__(64) void mlp_kernel(
    const float* __restrict__ se, const float* __restrict__ sez,
    const float* __restrict__ m1w, const float* __restrict__ m1b,
    const float* __restrict__ m2w, const float* __restrict__ m2b,
    const float* __restrict__ m3w, const float* __restrict__ m3b,
    float* __restrict__ out)
{
    int gidx = blockIdx.x;
    int lane = threadIdx.x;
    float inv = 1.f / (se[gidx] + 1e-8f);
    float gz = (lane < LATENT) ? sez[gidx*LATENT + lane] * inv : 0.f;

    // layer 1: 32 -> 128 ; lane holds hidden[lane] (a0) and hidden[lane+64] (a1)
    float a0 = m1b[lane], a1 = m1b[lane + 64];
    #pragma unroll
    for (int k = 0; k < LATENT; ++k) {
        float zk = __shfl(gz, k);
        a0 = fmaf(zk, m1w[k*128 + lane], a0);
        a1 = fmaf(zk, m1w[k*128 + lane + 64], a1);
    }
    a0 = fmaxf(a0, 0.f); a1 = fmaxf(a1, 0.f);

    // layer 2: 128 -> 64 ; lane holds out2[lane]
    float b = m2b[lane];
    #pragma unroll
    for (int k = 0; k < 64; ++k) {
        float xk = __shfl(a0, k);
        b = fmaf(xk, m2w[k*64 + lane], b);
    }
    #pragma unroll
    for (int k = 0; k < 64; ++k) {
        float xk = __shfl(a1, k);
        b = fmaf(xk, m2w[(k+64)*64 + lane], b);
    }
    b = fmaxf(b, 0.f);

    // layer 3: 64 -> 1 ; butterfly reduce, sigmoid
    float p = b * m3w[lane];
    #pragma unroll
    for (int s = 32; s >= 1; s >>= 1)
        p += __shfl_xor(p, s);
    if (lane == 0)
        out[gidx] = 1.f / (1.f + __expf(-(p + m3b[0])));
}

extern "C" void kernel_launch(void* const* d_in, const int* in_sizes, int n_in,
                              void* d_out, int out_size, void* d_ws, size_t ws_size,
                              hipStream_t stream)
{
    const float* z    = (const float*)d_in[0];
    const int*   batch= (const int*)d_in[1];
    const float* aw1  = (const float*)d_in[2];
    const float* ab1  = (const float*)d_in[3];
    const float* aw2  = (const float*)d_in[4];
    const float* ab2  = (const float*)d_in[5];
    const float* m1w  = (const float*)d_in[6];
    const float* m1b  = (const float*)d_in[7];
    const float* m2w  = (const float*)d_in[8];
    const float* m2b  = (const float*)d_in[9];
    const float* m3w  = (const float*)d_in[10];
    const float* m3b  = (const float*)d_in[11];
    float* out = (float*)d_out;

    int n = in_sizes[0] / LATENT;   // 2,000,000 nodes

    float* se  = (float*)d_ws;          // [4096]
    float* sez = se + N_GRAPHS;         // [4096][32]

    // N_GRAPHS*33 floats = 135168 floats = 33792 float4 = 132 blocks * 256
    zero_ws_kernel<<<132, 256, 0, stream>>>((float4*)d_ws);

    int blocks = (n + 255) / 256;
    attn_seg_kernel<<<blocks, 256, 0, stream>>>(z, batch, aw1, ab1, aw2, ab2, se, sez, n);
    mlp_kernel<<<N_GRAPHS, 64, 0, stream>>>(se, sez, m1w, m1b, m2w, m2b, m3w, m3b, out);
}